// Round 4
// baseline (131.467 us; speedup 1.0000x reference)
//
#include <hip/hip_runtime.h>

typedef int v4i __attribute__((ext_vector_type(4)));

#define NIMG 32
#define CIN  256
#define COUT 256
#define HW   3136   // 56*56
#define W56  56
#define HP   58     // padded H/W
#define PIMG (HP * HP)                       // 3364
#define XQP_BYTES (NIMG * PIMG * CIN)        // 27,557,888
#define WP_BYTES  (9 * COUT * CIN)           // 589,824

#define BARRIER() asm volatile("s_barrier" ::: "memory")
#define VMCNT(n)  asm volatile("s_waitcnt vmcnt(" #n ")" ::: "memory")

// ---------------------------------------------------------------------------
// Kernel 0: zero only the pad border (228 px/image * 256B)
// ---------------------------------------------------------------------------
__global__ __launch_bounds__(256) void zero_border(v4i* __restrict__ p)
{
    int i = blockIdx.x * 256 + threadIdx.x;
    if (i >= NIMG * 228 * 16) return;
    int n = i / 3648, r = i % 3648, pix = r >> 4, c = r & 15;
    int h, w;
    if (pix < 58)       { h = 0;         w = pix;       }
    else if (pix < 116) { h = 57;        w = pix - 58;  }
    else if (pix < 172) { h = pix - 115; w = 0;         }
    else                { h = pix - 171; w = 57;        }
    v4i z = {0, 0, 0, 0};
    p[(size_t)(n * PIMG + h * HP + w) * 16 + c] = z;
}

// ---------------------------------------------------------------------------
// Kernel 1: quantize + transpose  NCHW f32 -> padded NHWC int8 (interior)
// ---------------------------------------------------------------------------
__global__ __launch_bounds__(256) void quantize_pad(
    const float* __restrict__ x, signed char* __restrict__ xqp)
{
    __shared__ int tile[64][65];
    const int n  = blockIdx.z;
    const int c0 = blockIdx.y * 64;
    const int p0 = blockIdx.x * 64;
    const int tid = threadIdx.x;

    const int px   = tid & 63;
    const int crow = tid >> 6;
    const float* xb = x + ((size_t)(n * CIN + c0)) * HW + p0;
#pragma unroll
    for (int i = 0; i < 16; ++i) {
        int c = crow + i * 4;
        float v = xb[(size_t)c * HW + px];
        v = fminf(fmaxf(v, -1.f), 1.f);
        tile[c][px] = (int)rintf(v * 127.f);
    }
    __syncthreads();

    const int c4   = tid & 15;
    const int prow = tid >> 4;
#pragma unroll
    for (int i = 0; i < 4; ++i) {
        int p  = prow + i * 16;
        int hw = p0 + p;
        int oh = hw / W56, ow = hw % W56;
        int b0 = tile[c4 * 4 + 0][p] & 255;
        int b1 = tile[c4 * 4 + 1][p] & 255;
        int b2 = tile[c4 * 4 + 2][p] & 255;
        int b3 = tile[c4 * 4 + 3][p] & 255;
        int packed = b0 | (b1 << 8) | (b2 << 16) | (b3 << 24);
        *(int*)(xqp + ((size_t)(n * PIMG + (oh + 1) * HP + (ow + 1))) * CIN
                    + c0 + c4 * 4) = packed;
    }
}

// ---------------------------------------------------------------------------
// Kernel 2: weight repack  OIHW int32{-1,0,1} -> [step 0..35][cout 256][64B]
// ---------------------------------------------------------------------------
__global__ __launch_bounds__(256) void repack_w(
    const int* __restrict__ wq, signed char* __restrict__ wp2)
{
    int idx  = blockIdx.x * 256 + threadIdx.x;   // < 589824
    int t    = idx >> 16;
    int rem  = idx & 65535;
    int kc   = rem >> 14;
    int rem2 = rem & 16383;
    int co   = rem2 >> 6;
    int c6   = rem2 & 63;
    int ci   = kc * 64 + c6;
    wp2[idx] = (signed char)wq[(co * CIN + ci) * 9 + t];
}

// ---------------------------------------------------------------------------
// Kernel 3: phased implicit-GEMM conv. Tile 128 cout x 256 px, BK=64,
// 4 waves each 64 cout x 128 px (32 MFMA : 12 ds_read per step),
// 3-deep LDS pipeline, counted vmcnt, swizzled LDS, setprio MFMA phases.
// ---------------------------------------------------------------------------
__device__ __forceinline__ void gll16(const void* g, void* l)
{
    __builtin_amdgcn_global_load_lds(
        (const __attribute__((address_space(1))) int*)g,
        (__attribute__((address_space(3))) int*)l, 16, 0, 0);
}

__global__ __launch_bounds__(256) void bitconv_mfma(
    const signed char* __restrict__ xqp, const signed char* __restrict__ wp2,
    const float* __restrict__ s_, const float* __restrict__ bias,
    const float* __restrict__ act_s_p, float* __restrict__ out)
{
    // per buffer: A 8KB (128 cout x 64B), B 16KB (256 px x 64B)
    __shared__ signed char lds[3][24576];

    const int tid  = threadIdx.x;
    const int lane = tid & 63;
    const int wid  = tid >> 6;          // 0..3
    const int wr   = wid >> 1;          // cout half
    const int wc   = wid & 1;           // px half (128 px each)
    const int l15  = lane & 15;
    const int kg   = lane >> 4;
    const int kgs  = ((kg ^ ((l15 >> 1) & 3)) << 4);   // swizzled chunk

    // XCD-bijective swizzle (784 % 8 == 0): pair cout-halves on one XCD
    const int b  = blockIdx.x;
    const int w  = (b & 7) * 98 + (b >> 3);
    const int px0   = (w >> 1) * 256;
    const int cout0 = (w & 1) * 128;

    // ---- staging addresses (swizzle baked into the global source) ----
    const int srow   = tid >> 2;                         // 0..63
    const int schunk = (((tid & 3) ^ ((tid >> 3) & 3)) << 4);
    const signed char* asrc = wp2 + cout0 * 64 + srow * 64 + schunk;

    const signed char* bsrc[4];
#pragma unroll
    for (int r = 0; r < 4; ++r) {
        int p = px0 + srow + r * 64;
        int n = p / HW, q = p % HW;
        bsrc[r] = xqp
            + ((size_t)(n * PIMG + (q / W56 + 1) * HP + (q % W56 + 1))) * CIN
            + schunk;
    }

    // ---- fragment ds_read offsets (swizzled) ----
    int aoff[4], boff[8];
#pragma unroll
    for (int i = 0; i < 4; ++i)
        aoff[i] = (wr * 64 + i * 16 + l15) * 64 + kgs;
#pragma unroll
    for (int j = 0; j < 8; ++j)
        boff[j] = 8192 + (wc * 128 + j * 16 + l15) * 64 + kgs;

    v4i acc[4][8] = {};

    const int wb = wid * 1024;          // wave-uniform LDS sub-base

    auto stage = [&](int buf, int s) {
        int t9 = s >> 2, kc = s & 3;
        int bo = ((t9 / 3 - 1) * HP + (t9 % 3 - 1)) * CIN + kc * 64;
        signed char* L = &lds[buf][0];
        const signed char* a = asrc + s * 16384;
        gll16(a,            L + wb);             // A rows 0..63
        gll16(a + 4096,     L + 4096  + wb);     // A rows 64..127
        gll16(bsrc[0] + bo, L + 8192  + wb);
        gll16(bsrc[1] + bo, L + 12288 + wb);
        gll16(bsrc[2] + bo, L + 16384 + wb);
        gll16(bsrc[3] + bo, L + 20480 + wb);
    };

    // prologue: steps 0 and 1 staged; wait for step 0's 6 loads
    stage(0, 0);
    stage(1, 1);
    VMCNT(6);
    BARRIER();

    for (int it = 0; it < 12; ++it) {
#pragma unroll
        for (int u = 0; u < 3; ++u) {
            const int s = it * 3 + u;
            const signed char* L = &lds[u][0];

            if (s <= 33) stage((u + 2) % 3, s + 2);   // issue-early (T3)

            v4i a[4], bb[8];
#pragma unroll
            for (int i = 0; i < 4; ++i) a[i]  = *(const v4i*)(L + aoff[i]);
#pragma unroll
            for (int j = 0; j < 8; ++j) bb[j] = *(const v4i*)(L + boff[j]);

            BARRIER();                 // all reads/stages issued
            __builtin_amdgcn_s_setprio(1);
#pragma unroll
            for (int i = 0; i < 2; ++i)
#pragma unroll
                for (int j = 0; j < 8; ++j)
                    acc[i][j] = __builtin_amdgcn_mfma_i32_16x16x64_i8(
                        a[i], bb[j], acc[i][j], 0, 0, 0);
            __builtin_amdgcn_s_setprio(0);

            BARRIER();                 // phase split (role diversity)
            __builtin_amdgcn_s_setprio(1);
#pragma unroll
            for (int i = 2; i < 4; ++i)
#pragma unroll
                for (int j = 0; j < 8; ++j)
                    acc[i][j] = __builtin_amdgcn_mfma_i32_16x16x64_i8(
                        a[i], bb[j], acc[i][j], 0, 0, 0);
            __builtin_amdgcn_s_setprio(0);

            // counted vmcnt: step s+1's 6 loads done, newest 6 stay in flight
            if (s <= 33)      { VMCNT(6); }
            else if (s == 34) { VMCNT(0); }
            if (s < 35) BARRIER();
        }
    }

    // ---- epilogue: y = acc * (act_s * s[c]) + bias[c], NCHW f32 ----
    const float a_s = act_s_p[0];
    int nn[8], hh[8];
#pragma unroll
    for (int j = 0; j < 8; ++j) {
        int op = px0 + wc * 128 + j * 16 + l15;
        nn[j] = op / HW;
        hh[j] = op % HW;
    }
#pragma unroll
    for (int i = 0; i < 4; ++i) {
        int cb = cout0 + wr * 64 + i * 16 + kg * 4;
        float sc[4], bi[4];
#pragma unroll
        for (int r = 0; r < 4; ++r) {
            sc[r] = a_s * s_[cb + r];
            bi[r] = bias[cb + r];
        }
#pragma unroll
        for (int j = 0; j < 8; ++j)
#pragma unroll
            for (int r = 0; r < 4; ++r)
                out[((size_t)(nn[j] * COUT + cb + r)) * HW + hh[j]] =
                    (float)acc[i][j][r] * sc[r] + bi[r];
    }
}

// ---------------------------------------------------------------------------
extern "C" void kernel_launch(void* const* d_in, const int* in_sizes, int n_in,
                              void* d_out, int out_size, void* d_ws, size_t ws_size,
                              hipStream_t stream)
{
    const float* x     = (const float*)d_in[0];
    const int*   w_q   = (const int*)d_in[1];
    const float* s     = (const float*)d_in[2];
    const float* bias  = (const float*)d_in[3];
    const float* act_s = (const float*)d_in[4];

    signed char* xqp = (signed char*)d_ws;
    signed char* wp2 = (signed char*)d_ws + XQP_BYTES;

    zero_border<<<(NIMG * 228 * 16 + 255) / 256, 256, 0, stream>>>((v4i*)xqp);
    quantize_pad<<<dim3(49, 4, NIMG), 256, 0, stream>>>(x, xqp);
    repack_w<<<dim3(WP_BYTES / 256), 256, 0, stream>>>(w_q, wp2);
    bitconv_mfma<<<dim3(784), 256, 0, stream>>>(
        xqp, wp2, s, bias, act_s, (float*)d_out);
}

// Round 5
// 99.336 us; speedup vs baseline: 1.3235x; 1.3235x over previous
//
#include <hip/hip_runtime.h>

typedef int v4i __attribute__((ext_vector_type(4)));

#define NIMG 32
#define CIN  256
#define COUT 256
#define HW   3136   // 56*56
#define W56  56
#define HP   58     // padded H/W
#define PIMG (HP * HP)                       // 3364
#define XQP_BYTES (NIMG * PIMG * CIN)        // 27,557,888
#define WP_BYTES  (9 * COUT * CIN)           // 589,824

#define BARRIER() asm volatile("s_barrier" ::: "memory")
#define VMCNT(n)  asm volatile("s_waitcnt vmcnt(" #n ")" ::: "memory")

// ---------------------------------------------------------------------------
// Kernel 0: zero only the pad border (228 px/image * 256B)
// ---------------------------------------------------------------------------
__global__ __launch_bounds__(256) void zero_border(v4i* __restrict__ p)
{
    int i = blockIdx.x * 256 + threadIdx.x;
    if (i >= NIMG * 228 * 16) return;
    int n = i / 3648, r = i % 3648, pix = r >> 4, c = r & 15;
    int h, w;
    if (pix < 58)       { h = 0;         w = pix;       }
    else if (pix < 116) { h = 57;        w = pix - 58;  }
    else if (pix < 172) { h = pix - 115; w = 0;         }
    else                { h = pix - 171; w = 57;        }
    v4i z = {0, 0, 0, 0};
    p[(size_t)(n * PIMG + h * HP + w) * 16 + c] = z;
}

// ---------------------------------------------------------------------------
// Kernel 1: quantize + transpose  NCHW f32 -> padded NHWC int8 (interior)
// ---------------------------------------------------------------------------
__global__ __launch_bounds__(256) void quantize_pad(
    const float* __restrict__ x, signed char* __restrict__ xqp)
{
    __shared__ int tile[64][65];
    const int n  = blockIdx.z;
    const int c0 = blockIdx.y * 64;
    const int p0 = blockIdx.x * 64;
    const int tid = threadIdx.x;

    const int px   = tid & 63;
    const int crow = tid >> 6;
    const float* xb = x + ((size_t)(n * CIN + c0)) * HW + p0;
#pragma unroll
    for (int i = 0; i < 16; ++i) {
        int c = crow + i * 4;
        float v = xb[(size_t)c * HW + px];
        v = fminf(fmaxf(v, -1.f), 1.f);
        tile[c][px] = (int)rintf(v * 127.f);
    }
    __syncthreads();

    const int c4   = tid & 15;
    const int prow = tid >> 4;
#pragma unroll
    for (int i = 0; i < 4; ++i) {
        int p  = prow + i * 16;
        int hw = p0 + p;
        int oh = hw / W56, ow = hw % W56;
        int b0 = tile[c4 * 4 + 0][p] & 255;
        int b1 = tile[c4 * 4 + 1][p] & 255;
        int b2 = tile[c4 * 4 + 2][p] & 255;
        int b3 = tile[c4 * 4 + 3][p] & 255;
        int packed = b0 | (b1 << 8) | (b2 << 16) | (b3 << 24);
        *(int*)(xqp + ((size_t)(n * PIMG + (oh + 1) * HP + (ow + 1))) * CIN
                    + c0 + c4 * 4) = packed;
    }
}

// ---------------------------------------------------------------------------
// Kernel 2: weight repack  OIHW int32{-1,0,1} -> [step 0..35][cout 256][64B]
// ---------------------------------------------------------------------------
__global__ __launch_bounds__(256) void repack_w(
    const int* __restrict__ wq, signed char* __restrict__ wp2)
{
    int idx  = blockIdx.x * 256 + threadIdx.x;   // < 589824
    int t    = idx >> 16;
    int rem  = idx & 65535;
    int kc   = rem >> 14;
    int rem2 = rem & 16383;
    int co   = rem2 >> 6;
    int c6   = rem2 & 63;
    int ci   = kc * 64 + c6;
    wp2[idx] = (signed char)wq[(co * CIN + ci) * 9 + t];
}

// ---------------------------------------------------------------------------
// Kernel 3: phased implicit-GEMM conv. Tile 128 cout x 128 px, BK=64,
// 4 waves (2x2) of 64x64 (16 MFMA : 8 ds_read per step, R3-proven ratio),
// 3-deep LDS pipeline (48KB -> 3 blocks/CU), counted vmcnt, swizzled LDS,
// setprio MFMA phases, grid 1568 (tail 2.04 rounds, XCD-bijective).
// ---------------------------------------------------------------------------
__device__ __forceinline__ void gll16(const void* g, void* l)
{
    __builtin_amdgcn_global_load_lds(
        (const __attribute__((address_space(1))) int*)g,
        (__attribute__((address_space(3))) int*)l, 16, 0, 0);
}

__global__ __launch_bounds__(256) void bitconv_mfma(
    const signed char* __restrict__ xqp, const signed char* __restrict__ wp2,
    const float* __restrict__ s_, const float* __restrict__ bias,
    const float* __restrict__ act_s_p, float* __restrict__ out)
{
    // per buffer: A 8KB (128 cout x 64B) + B 8KB (128 px x 64B)
    __shared__ signed char lds[3][16384];

    const int tid  = threadIdx.x;
    const int lane = tid & 63;
    const int wid  = tid >> 6;          // 0..3
    const int wr   = wid >> 1;          // cout half
    const int wc   = wid & 1;           // px half
    const int l15  = lane & 15;
    const int kg   = lane >> 4;
    const int kgs  = ((kg ^ ((l15 >> 1) & 3)) << 4);   // swizzled chunk

    // XCD-bijective swizzle (1568 % 8 == 0): pair cout-halves on one XCD
    const int b  = blockIdx.x;
    const int w  = (b & 7) * 196 + (b >> 3);
    const int px0   = (w >> 1) * 128;
    const int cout0 = (w & 1) * 128;

    // ---- staging addresses (swizzle baked into the global source) ----
    const int srow   = tid >> 2;                         // 0..63
    const int schunk = (((tid & 3) ^ ((tid >> 3) & 3)) << 4);
    const signed char* asrc = wp2 + cout0 * 64 + srow * 64 + schunk;

    const signed char* bsrc[2];
#pragma unroll
    for (int r = 0; r < 2; ++r) {
        int p = px0 + srow + r * 64;
        int n = p / HW, q = p % HW;
        bsrc[r] = xqp
            + ((size_t)(n * PIMG + (q / W56 + 1) * HP + (q % W56 + 1))) * CIN
            + schunk;
    }

    // ---- fragment ds_read offsets (swizzled) ----
    int aoff[4], boff[4];
#pragma unroll
    for (int i = 0; i < 4; ++i)
        aoff[i] = (wr * 64 + i * 16 + l15) * 64 + kgs;
#pragma unroll
    for (int j = 0; j < 4; ++j)
        boff[j] = 8192 + (wc * 64 + j * 16 + l15) * 64 + kgs;

    v4i acc[4][4] = {};

    const int wb = wid * 1024;          // wave-uniform LDS sub-base

    auto stage = [&](int buf, int s) {
        int t9 = s >> 2, kc = s & 3;
        int bo = ((t9 / 3 - 1) * HP + (t9 % 3 - 1)) * CIN + kc * 64;
        signed char* L = &lds[buf][0];
        const signed char* a = asrc + s * 16384;
        gll16(a,            L + wb);             // A rows 0..63
        gll16(a + 4096,     L + 4096  + wb);     // A rows 64..127
        gll16(bsrc[0] + bo, L + 8192  + wb);     // B rows 0..63
        gll16(bsrc[1] + bo, L + 12288 + wb);     // B rows 64..127
    };

    // prologue: steps 0 and 1 staged; wait for step 0's 4 loads
    stage(0, 0);
    stage(1, 1);
    VMCNT(4);
    BARRIER();

    for (int it = 0; it < 12; ++it) {
#pragma unroll
        for (int u = 0; u < 3; ++u) {
            const int s = it * 3 + u;
            const signed char* L = &lds[u][0];

            if (s <= 33) stage((u + 2) % 3, s + 2);   // issue-early (T3)

            v4i a[4], bb[4];
#pragma unroll
            for (int i = 0; i < 4; ++i) a[i]  = *(const v4i*)(L + aoff[i]);
#pragma unroll
            for (int j = 0; j < 4; ++j) bb[j] = *(const v4i*)(L + boff[j]);

            BARRIER();                 // all reads/stages issued
            __builtin_amdgcn_s_setprio(1);
#pragma unroll
            for (int i = 0; i < 2; ++i)
#pragma unroll
                for (int j = 0; j < 4; ++j)
                    acc[i][j] = __builtin_amdgcn_mfma_i32_16x16x64_i8(
                        a[i], bb[j], acc[i][j], 0, 0, 0);
            __builtin_amdgcn_s_setprio(0);

            BARRIER();                 // phase split (role diversity)
            __builtin_amdgcn_s_setprio(1);
#pragma unroll
            for (int i = 2; i < 4; ++i)
#pragma unroll
                for (int j = 0; j < 4; ++j)
                    acc[i][j] = __builtin_amdgcn_mfma_i32_16x16x64_i8(
                        a[i], bb[j], acc[i][j], 0, 0, 0);
            __builtin_amdgcn_s_setprio(0);

            // counted vmcnt: step s+1's 4 loads done, newest 4 stay in flight
            if (s <= 33)      { VMCNT(4); }
            else if (s == 34) { VMCNT(0); }
            if (s < 35) BARRIER();
        }
    }

    // ---- epilogue: y = acc * (act_s * s[c]) + bias[c], NCHW f32 ----
    const float a_s = act_s_p[0];
    int nn[4], hh[4];
#pragma unroll
    for (int j = 0; j < 4; ++j) {
        int op = px0 + wc * 64 + j * 16 + l15;
        nn[j] = op / HW;
        hh[j] = op % HW;
    }
#pragma unroll
    for (int i = 0; i < 4; ++i) {
        int cb = cout0 + wr * 64 + i * 16 + kg * 4;
        float sc[4], bi[4];
#pragma unroll
        for (int r = 0; r < 4; ++r) {
            sc[r] = a_s * s_[cb + r];
            bi[r] = bias[cb + r];
        }
#pragma unroll
        for (int j = 0; j < 4; ++j)
#pragma unroll
            for (int r = 0; r < 4; ++r)
                out[((size_t)(nn[j] * COUT + cb + r)) * HW + hh[j]] =
                    (float)acc[i][j][r] * sc[r] + bi[r];
    }
}

// ---------------------------------------------------------------------------
extern "C" void kernel_launch(void* const* d_in, const int* in_sizes, int n_in,
                              void* d_out, int out_size, void* d_ws, size_t ws_size,
                              hipStream_t stream)
{
    const float* x     = (const float*)d_in[0];
    const int*   w_q   = (const int*)d_in[1];
    const float* s     = (const float*)d_in[2];
    const float* bias  = (const float*)d_in[3];
    const float* act_s = (const float*)d_in[4];

    signed char* xqp = (signed char*)d_ws;
    signed char* wp2 = (signed char*)d_ws + XQP_BYTES;

    zero_border<<<(NIMG * 228 * 16 + 255) / 256, 256, 0, stream>>>((v4i*)xqp);
    quantize_pad<<<dim3(49, 4, NIMG), 256, 0, stream>>>(x, xqp);
    repack_w<<<dim3(WP_BYTES / 256), 256, 0, stream>>>(w_q, wp2);
    bitconv_mfma<<<dim3(1568), 256, 0, stream>>>(
        xqp, wp2, s, bias, act_s, (float*)d_out);
}

// Round 6
// 98.705 us; speedup vs baseline: 1.3319x; 1.0064x over previous
//
#include <hip/hip_runtime.h>

typedef int v4i __attribute__((ext_vector_type(4)));

#define NIMG 32
#define CIN  256
#define COUT 256
#define HW   3136   // 56*56
#define W56  56
#define HP   58     // padded H/W
#define PIMG (HP * HP)                       // 3364
#define XQP_BYTES (NIMG * PIMG * CIN)        // 27,557,888
#define WP_BYTES  (9 * COUT * CIN)           // 589,824

#define BARRIER() asm volatile("s_barrier" ::: "memory")
#define VMCNT(n)  asm volatile("s_waitcnt vmcnt(" #n ")" ::: "memory")

// ---------------------------------------------------------------------------
// Kernel 0: zero only the pad border (228 px/image * 256B)
// ---------------------------------------------------------------------------
__global__ __launch_bounds__(256) void zero_border(v4i* __restrict__ p)
{
    int i = blockIdx.x * 256 + threadIdx.x;
    if (i >= NIMG * 228 * 16) return;
    int n = i / 3648, r = i % 3648, pix = r >> 4, c = r & 15;
    int h, w;
    if (pix < 58)       { h = 0;         w = pix;       }
    else if (pix < 116) { h = 57;        w = pix - 58;  }
    else if (pix < 172) { h = pix - 115; w = 0;         }
    else                { h = pix - 171; w = 57;        }
    v4i z = {0, 0, 0, 0};
    p[(size_t)(n * PIMG + h * HP + w) * 16 + c] = z;
}

// ---------------------------------------------------------------------------
// Kernel 1: quantize + transpose  NCHW f32 -> padded NHWC int8 (interior)
// ---------------------------------------------------------------------------
__global__ __launch_bounds__(256) void quantize_pad(
    const float* __restrict__ x, signed char* __restrict__ xqp)
{
    __shared__ int tile[64][65];
    const int n  = blockIdx.z;
    const int c0 = blockIdx.y * 64;
    const int p0 = blockIdx.x * 64;
    const int tid = threadIdx.x;

    const int px   = tid & 63;
    const int crow = tid >> 6;
    const float* xb = x + ((size_t)(n * CIN + c0)) * HW + p0;
#pragma unroll
    for (int i = 0; i < 16; ++i) {
        int c = crow + i * 4;
        float v = xb[(size_t)c * HW + px];
        v = fminf(fmaxf(v, -1.f), 1.f);
        tile[c][px] = (int)rintf(v * 127.f);
    }
    __syncthreads();

    const int c4   = tid & 15;
    const int prow = tid >> 4;
#pragma unroll
    for (int i = 0; i < 4; ++i) {
        int p  = prow + i * 16;
        int hw = p0 + p;
        int oh = hw / W56, ow = hw % W56;
        int b0 = tile[c4 * 4 + 0][p] & 255;
        int b1 = tile[c4 * 4 + 1][p] & 255;
        int b2 = tile[c4 * 4 + 2][p] & 255;
        int b3 = tile[c4 * 4 + 3][p] & 255;
        int packed = b0 | (b1 << 8) | (b2 << 16) | (b3 << 24);
        *(int*)(xqp + ((size_t)(n * PIMG + (oh + 1) * HP + (ow + 1))) * CIN
                    + c0 + c4 * 4) = packed;
    }
}

// ---------------------------------------------------------------------------
// Kernel 2: weight repack  OIHW int32{-1,0,1} -> [step 0..35][cout 256][64B]
// ---------------------------------------------------------------------------
__global__ __launch_bounds__(256) void repack_w(
    const int* __restrict__ wq, signed char* __restrict__ wp2)
{
    int idx  = blockIdx.x * 256 + threadIdx.x;   // < 589824
    int t    = idx >> 16;
    int rem  = idx & 65535;
    int kc   = rem >> 14;
    int rem2 = rem & 16383;
    int co   = rem2 >> 6;
    int c6   = rem2 & 63;
    int ci   = kc * 64 + c6;
    wp2[idx] = (signed char)wq[(co * CIN + ci) * 9 + t];
}

// ---------------------------------------------------------------------------
// Kernel 3: phased implicit-GEMM conv (m201-style).
// Block 256 cout x 128 px, BK=64, 4 waves (2Mx2N), per-wave 128x64
// (12 ds_read : 32 MFMA). Two phases per K-step, each
// {ds_read subtile | stage part | barrier | 16 MFMA | barrier}.
// 3-deep LDS (72KB, 2 blocks/CU), counted VMCNT(6) at step end only.
// ---------------------------------------------------------------------------
__device__ __forceinline__ void gll16(const void* g, void* l)
{
    __builtin_amdgcn_global_load_lds(
        (const __attribute__((address_space(1))) int*)g,
        (__attribute__((address_space(3))) int*)l, 16, 0, 0);
}

__global__ __launch_bounds__(256, 2) void bitconv_mfma(
    const signed char* __restrict__ xqp, const signed char* __restrict__ wp2,
    const float* __restrict__ s_, const float* __restrict__ bias,
    const float* __restrict__ act_s_p, float* __restrict__ out)
{
    // per buffer: A 16KB (256 cout x 64B) + B 8KB (128 px x 64B)
    __shared__ signed char lds[3][24576];

    const int tid  = threadIdx.x;
    const int lane = tid & 63;
    const int wid  = tid >> 6;          // 0..3
    const int wr   = wid >> 1;          // cout half (128 each)
    const int wc   = wid & 1;           // px half (64 each)
    const int l15  = lane & 15;
    const int kg   = lane >> 4;
    const int kgs  = ((kg ^ ((l15 >> 1) & 3)) << 4);   // swizzled chunk

    // XCD-bijective swizzle (784 % 8 == 0)
    const int b   = blockIdx.x;
    const int px0 = ((b & 7) * 98 + (b >> 3)) * 128;

    // ---- staging addresses (swizzle baked into the global source) ----
    const int srow   = tid >> 2;                         // 0..63
    const int schunk = (((tid & 3) ^ ((tid >> 3) & 3)) << 4);
    const signed char* asrc = wp2 + srow * 64 + schunk;  // + k*4096 rows

    const signed char* bsrc[2];
#pragma unroll
    for (int r = 0; r < 2; ++r) {
        int p = px0 + srow + r * 64;
        int n = p / HW, q = p % HW;
        bsrc[r] = xqp
            + ((size_t)(n * PIMG + (q / W56 + 1) * HP + (q % W56 + 1))) * CIN
            + schunk;
    }

    // ---- fragment ds_read offsets (swizzled) ----
    int aoff[8], boff[4];
#pragma unroll
    for (int i = 0; i < 8; ++i)
        aoff[i] = (wr * 128 + i * 16 + l15) * 64 + kgs;
#pragma unroll
    for (int j = 0; j < 4; ++j)
        boff[j] = 16384 + (wc * 64 + j * 16 + l15) * 64 + kgs;

    v4i acc[8][4] = {};

    const int wb = wid * 1024;          // wave-uniform LDS sub-base

    auto stageA = [&](int buf, int s) { // 4 gll16: A 16KB
        signed char* L = &lds[buf][0];
        const signed char* a = asrc + s * 16384;
#pragma unroll
        for (int k = 0; k < 4; ++k)
            gll16(a + k * 4096, L + k * 4096 + wb);
    };
    auto stageB = [&](int buf, int s) { // 2 gll16: B 8KB
        int t9 = s >> 2, kc = s & 3;
        int bo = ((t9 / 3 - 1) * HP + (t9 % 3 - 1)) * CIN + kc * 64;
        signed char* L = &lds[buf][0];
        gll16(bsrc[0] + bo, L + 16384 + wb);
        gll16(bsrc[1] + bo, L + 20480 + wb);
    };

    // prologue: steps 0,1 staged; wait step 0's 6 loads (6 stay in flight)
    stageA(0, 0); stageB(0, 0);
    stageA(1, 1); stageB(1, 1);
    VMCNT(6);
    BARRIER();

    for (int it = 0; it < 12; ++it) {
#pragma unroll
        for (int u = 0; u < 3; ++u) {
            const int s = it * 3 + u;
            const int nb = (u + 2) % 3;     // buffer being staged (s+2)
            const signed char* L = &lds[u][0];

            // ---- phase 0: read B + A-lo, stage next A ----
            v4i a[4], bb[4];
#pragma unroll
            for (int j = 0; j < 4; ++j) bb[j] = *(const v4i*)(L + boff[j]);
#pragma unroll
            for (int i = 0; i < 4; ++i) a[i]  = *(const v4i*)(L + aoff[i]);

            if (s <= 33) stageA(nb, s + 2);

            BARRIER();
            __builtin_amdgcn_s_setprio(1);
#pragma unroll
            for (int i = 0; i < 4; ++i)
#pragma unroll
                for (int j = 0; j < 4; ++j)
                    acc[i][j] = __builtin_amdgcn_mfma_i32_16x16x64_i8(
                        a[i], bb[j], acc[i][j], 0, 0, 0);
            __builtin_amdgcn_s_setprio(0);
            BARRIER();

            // ---- phase 1: read A-hi, stage next B ----
            v4i a2[4];
#pragma unroll
            for (int i = 0; i < 4; ++i) a2[i] = *(const v4i*)(L + aoff[4 + i]);

            if (s <= 33) stageB(nb, s + 2);

            BARRIER();
            __builtin_amdgcn_s_setprio(1);
#pragma unroll
            for (int i = 0; i < 4; ++i)
#pragma unroll
                for (int j = 0; j < 4; ++j)
                    acc[4 + i][j] = __builtin_amdgcn_mfma_i32_16x16x64_i8(
                        a2[i], bb[j], acc[4 + i][j], 0, 0, 0);
            __builtin_amdgcn_s_setprio(0);

            // counted vmcnt: s+1's 6 loads done, s+2's 6 stay in flight
            if (s <= 33)      { VMCNT(6); }
            else if (s == 34) { VMCNT(0); }
            if (s < 35) BARRIER();
        }
    }

    // ---- epilogue: y = acc * (act_s * s[c]) + bias[c], NCHW f32 ----
    const float a_s = act_s_p[0];
    int nn[4], hh[4];
#pragma unroll
    for (int j = 0; j < 4; ++j) {
        int op = px0 + wc * 64 + j * 16 + l15;
        nn[j] = op / HW;
        hh[j] = op % HW;
    }
#pragma unroll
    for (int i = 0; i < 8; ++i) {
        int cb = wr * 128 + i * 16 + kg * 4;
        float sc[4], bi[4];
#pragma unroll
        for (int r = 0; r < 4; ++r) {
            sc[r] = a_s * s_[cb + r];
            bi[r] = bias[cb + r];
        }
#pragma unroll
        for (int j = 0; j < 4; ++j)
#pragma unroll
            for (int r = 0; r < 4; ++r)
                out[((size_t)(nn[j] * COUT + cb + r)) * HW + hh[j]] =
                    (float)acc[i][j][r] * sc[r] + bi[r];
    }
}

// ---------------------------------------------------------------------------
extern "C" void kernel_launch(void* const* d_in, const int* in_sizes, int n_in,
                              void* d_out, int out_size, void* d_ws, size_t ws_size,
                              hipStream_t stream)
{
    const float* x     = (const float*)d_in[0];
    const int*   w_q   = (const int*)d_in[1];
    const float* s     = (const float*)d_in[2];
    const float* bias  = (const float*)d_in[3];
    const float* act_s = (const float*)d_in[4];

    signed char* xqp = (signed char*)d_ws;
    signed char* wp2 = (signed char*)d_ws + XQP_BYTES;

    zero_border<<<(NIMG * 228 * 16 + 255) / 256, 256, 0, stream>>>((v4i*)xqp);
    quantize_pad<<<dim3(49, 4, NIMG), 256, 0, stream>>>(x, xqp);
    repack_w<<<dim3(WP_BYTES / 256), 256, 0, stream>>>(w_q, wp2);
    bitconv_mfma<<<dim3(784), 256, 0, stream>>>(
        xqp, wp2, s, bias, act_s, (float*)d_out);
}